// Round 1
// baseline (243.830 us; speedup 1.0000x reference)
//
#include <hip/hip_runtime.h>

#define FEAT 512
#define F4 (FEAT / 4)   // 128 float4 per row
#define NSEG 1024

// Pass 1: segment boundary offsets. starts[s] = first row index with seg_id >= s.
// segment_ids are sorted, so row i is the start of every segment in (seg[i-1], seg[i]].
__global__ void seg_bounds_kernel(const int* __restrict__ seg,
                                  int* __restrict__ starts, int total) {
    int i = blockIdx.x * blockDim.x + threadIdx.x;
    if (i >= total) return;
    int cur = seg[i];
    int prev = (i == 0) ? -1 : seg[i - 1];
    for (int s = prev + 1; s <= cur; ++s) starts[s] = i;
    if (i == total - 1) {
        for (int s = cur + 1; s <= NSEG; ++s) starts[s] = total;
    }
}

// Pass 2: one block per segment. 512 threads = 4 row-groups x 128 lanes.
// Lane owns one float4 column (16B/lane coalesced). Read batch once,
// reduce across row-groups in LDS, broadcast mean back to all rows.
__global__ __launch_bounds__(512) void seg_mean_kernel(const float* __restrict__ batch,
                                                       const int* __restrict__ starts,
                                                       float* __restrict__ out) {
    const int s      = blockIdx.x;
    const int tid    = threadIdx.x;
    const int lane_f = tid & (F4 - 1);   // float4 column 0..127
    const int rgrp   = tid >> 7;         // row-group 0..3

    const int start = starts[s];
    const int end   = starts[s + 1];
    const int count = end - start;

    const float4* b4 = (const float4*)batch;
    float4 acc = make_float4(0.f, 0.f, 0.f, 0.f);
    for (int r = start + rgrp; r < end; r += 4) {
        float4 v = b4[(size_t)r * F4 + lane_f];
        acc.x += v.x; acc.y += v.y; acc.z += v.z; acc.w += v.w;
    }

    __shared__ float4 red[4][F4];
    red[rgrp][lane_f] = acc;
    __syncthreads();

    if (rgrp == 0) {
        float4 a = red[0][lane_f];
        float4 b = red[1][lane_f];
        float4 c = red[2][lane_f];
        float4 d = red[3][lane_f];
        const float inv = 1.0f / (float)(count > 0 ? count : 1);
        float4 m;
        m.x = (a.x + b.x + c.x + d.x) * inv;
        m.y = (a.y + b.y + c.y + d.y) * inv;
        m.z = (a.z + b.z + c.z + d.z) * inv;
        m.w = (a.w + b.w + c.w + d.w) * inv;
        red[0][lane_f] = m;
    }
    __syncthreads();

    const float4 mean = red[0][lane_f];
    float4* o4 = (float4*)out;
    for (int r = start + rgrp; r < end; r += 4) {
        o4[(size_t)r * F4 + lane_f] = mean;
    }
}

extern "C" void kernel_launch(void* const* d_in, const int* in_sizes, int n_in,
                              void* d_out, int out_size, void* d_ws, size_t ws_size,
                              hipStream_t stream) {
    const float* batch = (const float*)d_in[0];
    const int*   seg   = (const int*)d_in[1];
    float*       out   = (float*)d_out;
    const int total    = in_sizes[1];          // 262144 rows

    int* starts = (int*)d_ws;                   // NSEG+1 ints of scratch

    seg_bounds_kernel<<<(total + 255) / 256, 256, 0, stream>>>(seg, starts, total);
    seg_mean_kernel<<<NSEG, 512, 0, stream>>>(batch, starts, out);
}